// Round 13
// baseline (108.722 us; speedup 1.0000x reference)
//
#include <hip/hip_runtime.h>

#define B_SZ  2
#define N_PTS 16384
#define M_CTR 4096
#define C_FT  32
#define K_NB  32
#define NCH   35   // 3 + C_FT
#define CH_STRIDE (K_NB * M_CTR)   // 131072
#define CELLS 10
#define NCELL (CELLS * CELLS * CELLS)

// ---------------------------------------------------------------------------
// Exact single-rounded f32 ops, opaque to the compiler. v_fma_f32 ONLY where
// the numpy golden fuses (einsum cp accumulation). absmax==0.0 since R6 —
// DO NOT change the math.
// ---------------------------------------------------------------------------
__device__ __forceinline__ float fmul(float a, float b) {
    float r; asm("v_mul_f32 %0, %1, %2" : "=v"(r) : "v"(a), "v"(b)); return r;
}
__device__ __forceinline__ float fadd(float a, float b) {
    float r; asm("v_add_f32 %0, %1, %2" : "=v"(r) : "v"(a), "v"(b)); return r;
}
__device__ __forceinline__ float fsub(float a, float b) {
    float r; asm("v_sub_f32 %0, %1, %2" : "=v"(r) : "v"(a), "v"(b)); return r;
}
__device__ __forceinline__ float ffma(float a, float b, float c) {
    float r; asm("v_fma_f32 %0, %1, %2, %3" : "=v"(r) : "v"(a), "v"(b), "v"(c));
    return r;
}

__device__ __forceinline__ bool bq_valid(float x, float y, float z,
                                         float cx, float cy, float cz,
                                         float c2, float r2) {
    const float p2 = fadd(fadd(fmul(x, x), fmul(y, y)), fmul(z, z));
    const float cp = ffma(cz, z, ffma(cy, y, fmul(cx, x)));
    return fsub(fadd(c2, p2), fmul(2.0f, cp)) < r2;
}

__device__ __forceinline__ int cell_of(float x, float y, float z) {
    int ci = (int)(x * 10.0f); ci = ci < 0 ? 0 : (ci > 9 ? 9 : ci);
    int cj = (int)(y * 10.0f); cj = cj < 0 ? 0 : (cj > 9 ? 9 : cj);
    int ck = (int)(z * 10.0f); ck = ck < 0 ? 0 : (ck > 9 ? 9 : ck);
    return (ck * CELLS + cj) * CELLS + ci;   // x fastest
}

// ---------------------------------------------------------------------------
// Prep, ONE dispatch @1024 threads:
//   blocks 0..1   : per-batch LDS hist -> in-block shuffle-scan -> starts/cursor
//   blocks 2..513 : transpose points+feats -> pf (B,N,36), original n order
// ---------------------------------------------------------------------------
__global__ __launch_bounds__(1024) void prep_kernel(
    const float* __restrict__ points,   // (B,3,N)
    const float* __restrict__ feats,    // (B,C,N)
    int* __restrict__ starts,           // (B,1001)
    int* __restrict__ cursor,           // (B,1000)
    float* __restrict__ pf)             // (B,N,36)
{
    if (blockIdx.x < B_SZ) {
        const int b = blockIdx.x;
        const int t = threadIdx.x;
        const int lane = t & 63, wid = t >> 6;
        __shared__ int h[NCELL];
        __shared__ int wsum[16];
        for (int c = t; c < NCELL; c += 1024) h[c] = 0;
        __syncthreads();

        const float* __restrict__ px = points + (b * 3 + 0) * N_PTS;
        const float* __restrict__ py = points + (b * 3 + 1) * N_PTS;
        const float* __restrict__ pz = points + (b * 3 + 2) * N_PTS;
#pragma unroll
        for (int i = 0; i < 16; ++i) {
            const int n = t + i * 1024;
            atomicAdd(&h[cell_of(px[n], py[n], pz[n])], 1);
        }
        __syncthreads();

        const int v = (t < NCELL) ? h[t] : 0;
        int incl = v;
        for (int off = 1; off < 64; off <<= 1) {
            const int u = __shfl_up(incl, off);
            if (lane >= off) incl += u;
        }
        if (lane == 63) wsum[wid] = incl;
        __syncthreads();
        if (wid == 0 && lane < 16) {
            const int s = wsum[lane];
            int in2 = s;
            for (int off = 1; off < 16; off <<= 1) {
                const int u = __shfl_up(in2, off);
                if (lane >= off) in2 += u;
            }
            wsum[lane] = in2 - s;
        }
        __syncthreads();
        if (t < NCELL) {
            const int excl = incl - v + wsum[wid];
            starts[b * (NCELL + 1) + t] = excl;
            cursor[b * NCELL + t] = excl;
            if (t == NCELL - 1) starts[b * (NCELL + 1) + NCELL] = excl + v;
        }
    } else {
        __shared__ float tile[64][37];
        const int bid = blockIdx.x - B_SZ;
        const int t  = threadIdx.x;
        const int b  = bid >> 8;
        const int n0 = (bid & 255) * 64;
        for (int i = t; i < NCH * 64; i += 1024) {
            const int r = i >> 6;
            const int c = i & 63;
            float v;
            if (r < 3) v = points[(b * 3 + r) * N_PTS + n0 + c];
            else       v = feats[(b * C_FT + (r - 3)) * N_PTS + n0 + c];
            tile[c][r] = v;
        }
        if (t < 64) tile[t][35] = 0.0f;
        __syncthreads();
        float* __restrict__ dst = pf + ((size_t)b * N_PTS + n0) * 36;
        for (int o = t; o < 64 * 36; o += 1024) {
            const int c = o / 36;
            const int r = o - c * 36;
            dst[o] = tile[c][r];
        }
    }
}

// ---------------------------------------------------------------------------
// Scatter + record permute: thread per point n. Writes binned[t] (coords+n),
// inv[n]=t, and copies record pf[n] -> pf2[t] so gather can read records in
// BINNED (spatially clustered) order: consecutive centers share their
// 27-cell neighborhood -> their record reads collapse onto the same hot
// lines (L1/L2 reuse) instead of uniform-random L2-latency misses.
// ---------------------------------------------------------------------------
__global__ __launch_bounds__(256) void scatter_kernel(
    const float* __restrict__ points, int* __restrict__ cursor,
    float4* __restrict__ binned, int* __restrict__ inv,
    const float* __restrict__ pf, float* __restrict__ pf2) {
    const int t = blockIdx.x * 256 + threadIdx.x;
    const int b = t >> 14, n = t & (N_PTS - 1);
    const float x = points[(b * 3 + 0) * N_PTS + n];
    const float y = points[(b * 3 + 1) * N_PTS + n];
    const float z = points[(b * 3 + 2) * N_PTS + n];
    const int pos = atomicAdd(&cursor[b * NCELL + cell_of(x, y, z)], 1);
    binned[b * N_PTS + pos] = make_float4(x, y, z, __int_as_float(n));
    inv[b * N_PTS + n] = pos;
    const float4* __restrict__ src = (const float4*)(pf + ((size_t)b * N_PTS + n) * 36);
    float4* __restrict__ dst = (float4*)(pf2 + ((size_t)b * N_PTS + pos) * 36);
#pragma unroll
    for (int i = 0; i < 9; ++i) dst[i] = src[i];
}

// ---------------------------------------------------------------------------
// Ball query, binned. One wave per center; 27-cell neighborhood. Per-wave
// LDS bitmap over ORIGINAL n restores exact index order; emitted values are
// inv[n] = binned positions (gather reads pf2; output never contains the
// index itself, so this is value-identical).
// ---------------------------------------------------------------------------
__global__ __launch_bounds__(256) void ball_query_kernel(
    const float4* __restrict__ binned,   // (B,N) {x,y,z,idx}
    const float* __restrict__ centers,   // (B,3,M)
    const int* __restrict__ starts,      // (B,1001)
    const int* __restrict__ inv,         // (B,N) n -> binned pos
    int* __restrict__ idx_out)           // (B,K,M), holds binned positions
{
    const int lane = threadIdx.x & 63;
    const int wid  = threadIdx.x >> 6;
    const int cid  = blockIdx.x * 4 + wid;
    const int b = cid >> 12;
    const int m = cid & (M_CTR - 1);

    const float r2 = (float)(0.1 * 0.1);

    const float cx = centers[(b * 3 + 0) * M_CTR + m];
    const float cy = centers[(b * 3 + 1) * M_CTR + m];
    const float cz = centers[(b * 3 + 2) * M_CTR + m];
    const float c2 = fadd(fadd(fmul(cx, cx), fmul(cy, cy)), fmul(cz, cz));

    __shared__ unsigned bitmap[4][N_PTS / 32];   // 2 KB per wave
    unsigned* bm = bitmap[wid];
#pragma unroll
    for (int j = 0; j < 8; ++j) bm[lane * 8 + j] = 0u;

    int ci = (int)(cx * 10.0f); ci = ci < 0 ? 0 : (ci > 9 ? 9 : ci);
    int cj = (int)(cy * 10.0f); cj = cj < 0 ? 0 : (cj > 9 ? 9 : cj);
    int ck = (int)(cz * 10.0f); ck = ck < 0 ? 0 : (ck > 9 ? 9 : ck);
    const int i0 = ci > 0 ? ci - 1 : 0;
    const int i1 = ci < 9 ? ci + 1 : 9;
    const int* st = starts + b * (NCELL + 1);
    const float4* __restrict__ bp = binned + b * N_PTS;
    const int* __restrict__ invb = inv + b * N_PTS;

    for (int d = 0; d < 9; ++d) {
        const int jj = cj + (d % 3) - 1;
        const int kk = ck + (d / 3) - 1;
        if (jj < 0 || jj > 9 || kk < 0 || kk > 9) continue;
        const int base = (kk * CELLS + jj) * CELLS;
        const int lo = st[base + i0];
        const int hi = st[base + i1 + 1];
        for (int s0 = lo; s0 < hi; s0 += 64) {
            const int t = s0 + lane;
            if (t < hi) {
                const float4 p = bp[t];
                if (bq_valid(p.x, p.y, p.z, cx, cy, cz, c2, r2)) {
                    const int n = __float_as_int(p.w);
                    atomicOr((int*)&bm[n >> 5], 1 << (n & 31));
                }
            }
        }
    }

    unsigned w[8];
    int cnt = 0;
#pragma unroll
    for (int j = 0; j < 8; ++j) { w[j] = bm[lane * 8 + j]; cnt += __popc(w[j]); }

    int incl = cnt;
    for (int off = 1; off < 64; off <<= 1) {
        const int v = __shfl_up(incl, off);
        if (lane >= off) incl += v;
    }
    const int total = __shfl(incl, 63);
    int slot = incl - cnt;

    int firstbit = 0x7fffffff;
#pragma unroll
    for (int j = 0; j < 8; ++j) {
        if (w[j] && firstbit == 0x7fffffff)
            firstbit = lane * 256 + j * 32 + (__ffs(w[j]) - 1);
    }
    for (int off = 32; off > 0; off >>= 1)
        firstbit = min(firstbit, __shfl_xor(firstbit, off));
    const int first_t = invb[(total == 0) ? 0 : firstbit];

    int* __restrict__ dst = idx_out + (b * K_NB) * M_CTR + m;
#pragma unroll
    for (int j = 0; j < 8; ++j) {
        unsigned x = w[j];
        while (x && slot < K_NB) {
            const int bit = __ffs(x) - 1;
            dst[slot * M_CTR] = invb[lane * 256 + j * 32 + bit];
            x &= x - 1;
            ++slot;
        }
    }
    if (lane >= total && lane < K_NB) dst[lane * M_CTR] = first_t;
}

// ---------------------------------------------------------------------------
// Gather: 2 consecutive-m elements per thread, reading pf2 in binned order
// (spatially clustered record reads -> L1/L2 line reuse across neighboring
// centers). float2 plane stores (512 B/wave), int2 idx loads.
// ---------------------------------------------------------------------------
__global__ __launch_bounds__(256) void gather_kernel(
    const float* __restrict__ pf2,      // (B,N,36), binned order
    const float* __restrict__ centers,  // (B,3,M)
    const int* __restrict__ idx,        // (B,K,M), binned positions
    float* __restrict__ out)            // (B,35,K,M)
{
    const int t = blockIdx.x * 256 + threadIdx.x;   // 0..131071
    const int m = (t & (M_CTR / 2 - 1)) * 2;
    const int k = (t >> 11) & (K_NB - 1);
    const int b = t >> 16;

    const int2 nn = *(const int2*)&idx[(b * K_NB + k) * M_CTR + m];
    const float4* __restrict__ s0 =
        (const float4*)(pf2 + ((size_t)b * N_PTS + nn.x) * 36);
    const float4* __restrict__ s1 =
        (const float4*)(pf2 + ((size_t)b * N_PTS + nn.y) * 36);

    float4 f0[9], f1[9];
#pragma unroll
    for (int i = 0; i < 9; ++i) { f0[i] = s0[i]; f1[i] = s1[i]; }

    const float2 cx = *(const float2*)&centers[(b * 3 + 0) * M_CTR + m];
    const float2 cy = *(const float2*)&centers[(b * 3 + 1) * M_CTR + m];
    const float2 cz = *(const float2*)&centers[(b * 3 + 2) * M_CTR + m];

    float v0[36], v1[36];
#pragma unroll
    for (int i = 0; i < 9; ++i) {
        v0[4 * i + 0] = f0[i].x; v0[4 * i + 1] = f0[i].y;
        v0[4 * i + 2] = f0[i].z; v0[4 * i + 3] = f0[i].w;
        v1[4 * i + 0] = f1[i].x; v1[4 * i + 1] = f1[i].y;
        v1[4 * i + 2] = f1[i].z; v1[4 * i + 3] = f1[i].w;
    }
    v0[0] -= cx.x; v0[1] -= cy.x; v0[2] -= cz.x;   // single f32 subtract
    v1[0] -= cx.y; v1[1] -= cy.y; v1[2] -= cz.y;

    float* __restrict__ o = out + ((size_t)b * NCH * K_NB + k) * M_CTR + m;
#pragma unroll
    for (int ch = 0; ch < NCH; ++ch)
        *(float2*)&o[(size_t)ch * CH_STRIDE] = make_float2(v0[ch], v1[ch]);
}

extern "C" void kernel_launch(void* const* d_in, const int* in_sizes, int n_in,
                              void* d_out, int out_size, void* d_ws, size_t ws_size,
                              hipStream_t stream) {
    const float* points  = (const float*)d_in[0];
    const float* centers = (const float*)d_in[1];
    const float* feats   = (const float*)d_in[2];
    float* out = (float*)d_out;

    char* ws = (char*)d_ws;
    int*    idx    = (int*)ws;                                // 1 MiB
    float*  pf     = (float*)(ws + (1u << 20));               // 4.5 MiB
    float*  pf2    = (float*)(ws + 5767168u);                 // 4.5 MiB
    int*    cursor = (int*)(ws + 10485760u);                  // 8 KB
    int*    starts = (int*)(ws + 10485760u + 16384u);         // 8 KB
    int*    inv    = (int*)(ws + 10485760u + 32768u);         // 128 KB
    float4* binned = (float4*)(ws + 10485760u + 196608u);     // 512 KB

    prep_kernel<<<B_SZ + B_SZ * (N_PTS / 64), 1024, 0, stream>>>(
        points, feats, starts, cursor, pf);
    scatter_kernel<<<(B_SZ * N_PTS) / 256, 256, 0, stream>>>(
        points, cursor, binned, inv, pf, pf2);
    ball_query_kernel<<<(B_SZ * M_CTR) / 4, 256, 0, stream>>>(
        binned, centers, starts, inv, idx);
    gather_kernel<<<(B_SZ * K_NB * M_CTR / 2) / 256, 256, 0, stream>>>(
        pf2, centers, idx, out);
}